// Round 9
// baseline (288.840 us; speedup 1.0000x reference)
//
#include <hip/hip_runtime.h>
#include <hip/hip_bf16.h>

#define NT   32768
#define NH   2048
#define NE   128
#define TOPK 8
#define BTOK 32
#define BND    6.0e-4f
#define TWO_B  (2.0f * BND)

// ws layout (bytes):
//   [0,64):          u32 flagged-token counter
//   [64, 64+1MB):    Wt: B-fragment-ordered split-bf16 W (16B chunk g: lane=g&63,
//                    te=(g>>6)&7, s=(g>>9)&1, k32=g>>10)
//   [64+1MB, ...):   records, 32B each: u32 token, u32 cnt, 16x u8 cand ids
#define WS_W_OFF   64
#define WS_REC_U32 262160     // (64 + 1MB)/4

typedef __attribute__((ext_vector_type(8))) short bf16x8;
typedef __attribute__((ext_vector_type(4))) float f32x4;
typedef __attribute__((ext_vector_type(4))) unsigned int u32x4;

static __device__ __forceinline__ unsigned short f2bf(float f) {
    __hip_bfloat16 h = __float2bfloat16(f);
    return *reinterpret_cast<unsigned short*>(&h);
}

// ---------------- K0: build B-fragment-ordered W hi/lo chunks (RNE split) ----------------
__global__ __launch_bounds__(256) void prep_w_kernel(
    const float* __restrict__ W, unsigned short* __restrict__ Wt)
{
    int g = blockIdx.x * 256 + threadIdx.x;   // 65536 16B-per-lane chunks
    int lane = g & 63;
    int te   = (g >> 6) & 7;
    int s    = (g >> 9) & 1;
    int k32  = g >> 10;
    int row  = te * 16 + (lane & 15);
    int kb   = k32 * 32 + (lane >> 4) * 8;
    const float* src = W + (size_t)row * NH + kb;
    float4 f0 = *(const float4*)src;
    float4 f1 = *(const float4*)(src + 4);
    float f[8] = {f0.x, f0.y, f0.z, f0.w, f1.x, f1.y, f1.z, f1.w};
    bf16x8 o;
    #pragma unroll
    for (int e = 0; e < 8; ++e) {
        unsigned short h = f2bf(f[e]);
        if (s == 0) o[e] = (short)h;
        else {
            float fh = __builtin_bit_cast(float, ((unsigned int)h) << 16);
            o[e] = (short)f2bf(f[e] - fh);
        }
    }
    *(bf16x8*)(Wt + (size_t)g * 8) = o;
}

// ---------------- K1: 8-wave occupancy-max split-bf16 MFMA GEMM + fused select ----------------
// 512 thr = 8 waves; wave (g,h): tokens [t0+g*16, +16), K-quarter [h*512, +512).
__global__ __launch_bounds__(512, 4) void router_gemm_kernel(
    const float* __restrict__ X, const unsigned short* __restrict__ Wt,
    float* __restrict__ out, unsigned int* __restrict__ ws)
{
    __shared__ float ps[NE * 36];   // expert-major partials [128][36] = 18 KB

    const int tid  = threadIdx.x;
    const int lane = tid & 63;
    const int wv   = tid >> 6;          // 0..7
    const int g    = wv & 1;            // token half
    const int h    = wv >> 1;           // K quarter
    const int l15  = lane & 15, lhi = lane >> 4;
    const int t0   = blockIdx.x * BTOK;

    f32x4 acc[8];
    #pragma unroll
    for (int te = 0; te < 8; ++te) acc[te] = (f32x4){0.f, 0.f, 0.f, 0.f};

    const float* xrow = X + (size_t)(t0 + g * 16 + l15) * NH + h * 512 + lhi * 8;
    const unsigned short* wq = Wt + (size_t)(h * 16) * 8192 + lane * 8;

    // depth-1 rotated A loads; cheap bit-trick split (|x-ah-al| <= 3*2^-18|x|)
    float4 a0 = *(const float4*)(xrow);
    float4 a1 = *(const float4*)(xrow + 4);

    #pragma unroll
    for (int kk = 0; kk < 16; ++kk) {
        float4 n0, n1;
        if (kk < 15) {
            n0 = *(const float4*)(xrow + (kk + 1) * 32);
            n1 = *(const float4*)(xrow + (kk + 1) * 32 + 4);
        }
        bf16x8 ah, al;
        {
            float ff[8] = {a0.x, a0.y, a0.z, a0.w, a1.x, a1.y, a1.z, a1.w};
            unsigned int hu[4], lu[4];
            #pragma unroll
            for (int p = 0; p < 4; ++p) {
                unsigned int u0 = __builtin_bit_cast(unsigned int, ff[2 * p]);
                unsigned int u1 = __builtin_bit_cast(unsigned int, ff[2 * p + 1]);
                unsigned int r0 = u0 + 0x8000u, r1 = u1 + 0x8000u;
                hu[p] = (r0 >> 16) | (r1 & 0xFFFF0000u);
                float h0 = __builtin_bit_cast(float, r0 & 0xFFFF0000u);
                float h1 = __builtin_bit_cast(float, r1 & 0xFFFF0000u);
                float e0 = ff[2 * p] - h0, e1 = ff[2 * p + 1] - h1;
                unsigned int s0 = __builtin_bit_cast(unsigned int, e0);
                unsigned int s1 = __builtin_bit_cast(unsigned int, e1);
                lu[p] = (s0 >> 16) | (s1 & 0xFFFF0000u);    // truncated lo (fine: adds 2^-18)
            }
            ah = __builtin_bit_cast(bf16x8, (u32x4){hu[0], hu[1], hu[2], hu[3]});
            al = __builtin_bit_cast(bf16x8, (u32x4){lu[0], lu[1], lu[2], lu[3]});
        }
        const unsigned short* wb = wq + (size_t)kk * 8192;
        #pragma unroll
        for (int te = 0; te < 8; ++te) {
            bf16x8 bh = *(const bf16x8*)(wb + te * 512);
            bf16x8 bl = *(const bf16x8*)(wb + 4096 + te * 512);
            acc[te] = __builtin_amdgcn_mfma_f32_16x16x32_bf16(ah, bh, acc[te], 0, 0, 0);
            acc[te] = __builtin_amdgcn_mfma_f32_16x16x32_bf16(al, bh, acc[te], 0, 0, 0);
            acc[te] = __builtin_amdgcn_mfma_f32_16x16x32_bf16(ah, bl, acc[te], 0, 0, 0);
        }
        a0 = n0; a1 = n1;
    }

    // ---- cross-wave K reduction into expert-major ps[128][36] ----
    const int colbase = g * 16 + lhi * 4;
    #pragma unroll
    for (int hh = 0; hh < 4; ++hh) {
        if (h == hh) {
            #pragma unroll
            for (int te = 0; te < 8; ++te) {
                float* p = ps + (te * 16 + l15) * 36 + colbase;
                if (hh == 0) *(f32x4*)p = acc[te];
                else {
                    f32x4 v = *(f32x4*)p;
                    v += acc[te];
                    *(f32x4*)p = v;
                }
            }
        }
        __syncthreads();
    }

    // zero this block's dense score rows (32x128 f32 = 1024 float4)
    float* scoreBase = out + (size_t)t0 * NE;
    #pragma unroll
    for (int q = 0; q < 2; ++q) {
        int i = tid + q * 512;
        *(float4*)(scoreBase + (size_t)i * 4) = make_float4(0.f, 0.f, 0.f, 0.f);
    }
    __syncthreads();

    // ---- per-token epilogue: top-13 insert-sort, gap check, flag ----
    if (tid < BTOK) {
        float tv[13]; int ti[13];
        #pragma unroll
        for (int k = 0; k < 13; ++k) { tv[k] = -3.0e38f; ti[k] = 0; }
        for (int e = 0; e < NE; ++e) {
            float v = ps[e * 36 + tid];
            if (v > tv[12]) {
                float cv = v; int ci = e;
                #pragma unroll
                for (int s = 0; s < 13; ++s) {
                    if (cv > tv[s]) {
                        float t1 = tv[s]; int t2 = ti[s];
                        tv[s] = cv; ti[s] = ci; cv = t1; ci = t2;
                    }
                }
            }
        }
        bool flag = false;
        #pragma unroll
        for (int k = 0; k < 8; ++k) flag |= (tv[k] - tv[k + 1] < TWO_B);

        float pv[8]; float ksum = 0.f;
        #pragma unroll
        for (int k = 0; k < 8; ++k) { pv[k] = expf(tv[k] - tv[0]); ksum += pv[k]; }
        const int tg = t0 + tid;
        float* srow = out + (size_t)tg * NE;
        float* irow = out + (size_t)NT * NE + (size_t)tg * TOPK;
        #pragma unroll
        for (int k = 0; k < 8; ++k) {
            srow[ti[k]] = pv[k] / ksum;
            irow[k] = (float)ti[k];
        }

        if (flag) {
            unsigned int cnt;
            unsigned int idw[4] = {0u, 0u, 0u, 0u};
            float thr = tv[7] - TWO_B;
            if (tv[12] >= thr) {
                cnt = 0xFFu;
            } else {
                cnt = 0;
                #pragma unroll
                for (int k = 0; k < 13; ++k) {
                    if (k < 8 || tv[k] >= thr) {
                        idw[cnt >> 2] |= ((unsigned int)ti[k]) << ((cnt & 3) * 8);
                        ++cnt;
                    }
                }
            }
            unsigned int slot = atomicAdd(ws, 1u);
            unsigned int* rec = ws + WS_REC_U32 + slot * 8;
            rec[0] = (unsigned int)tg;
            rec[1] = cnt;
            rec[2] = idw[0]; rec[3] = idw[1]; rec[4] = idw[2]; rec[5] = idw[3];
        }
    }
}

// ---------------- K2: f64 refine flagged tokens ----------------
__global__ __launch_bounds__(256) void finalize_kernel(
    const float* __restrict__ X, const float* __restrict__ W,
    float* __restrict__ out, const unsigned int* __restrict__ ws)
{
    __shared__ float  xs[2048];
    __shared__ double cv[128];
    __shared__ int    cid[128];
    __shared__ float  ovals[8];
    __shared__ int    oidx[8];

    const int tid = threadIdx.x;
    const int lane = tid & 63, w = tid >> 6;
    const unsigned int n = ws[0];

    for (unsigned int rI = blockIdx.x; rI < n; rI += gridDim.x) {
        const unsigned int* rec = ws + WS_REC_U32 + rI * 8;
        const int tg = (int)rec[0];
        const unsigned int cnt = rec[1];
        const unsigned char* ids = (const unsigned char*)(rec + 2);
        const int nc = (cnt == 0xFFu) ? NE : (int)cnt;

        #pragma unroll
        for (int q = 0; q < 2; ++q) {
            int i = tid + q * 256;
            *(float4*)(xs + i * 4) = *(const float4*)(X + (size_t)tg * NH + i * 4);
        }
        __syncthreads();

        for (int c = w; c < nc; c += 4) {
            int e = (cnt == 0xFFu) ? c : (int)ids[c];
            const float* wrow = W + (size_t)e * NH;
            double s = 0.0;
            #pragma unroll
            for (int m = 0; m < 8; ++m) {
                float4 wv = *(const float4*)(wrow + m * 256 + lane * 4);
                float4 xv = *(const float4*)(xs + m * 256 + lane * 4);
                s = fma((double)xv.x, (double)wv.x, s);
                s = fma((double)xv.y, (double)wv.y, s);
                s = fma((double)xv.z, (double)wv.z, s);
                s = fma((double)xv.w, (double)wv.w, s);
            }
            #pragma unroll
            for (int off = 32; off >= 1; off >>= 1) s += __shfl_xor(s, off);
            if (lane == 0) { cv[c] = s; cid[c] = e; }
        }
        __syncthreads();

        if (tid == 0) {
            double lv[8];
            #pragma unroll
            for (int k = 0; k < 8; ++k) {
                double best = -1.0e300; int bi = 1 << 30, bc = 0;
                for (int c = 0; c < nc; ++c) {
                    double v = cv[c]; int e = cid[c];
                    if (v > best || (v == best && e < bi)) { best = v; bi = e; bc = c; }
                }
                lv[k] = best; oidx[k] = bi; cv[bc] = -1.0e301;
            }
            double m = lv[0], sum = 0.0, p[8];
            #pragma unroll
            for (int k = 0; k < 8; ++k) { p[k] = exp(lv[k] - m); sum += p[k]; }
            #pragma unroll
            for (int k = 0; k < 8; ++k) ovals[k] = (float)(p[k] / sum);
        }
        __syncthreads();

        float* srow = out + (size_t)tg * NE;
        if (tid < NE) {
            float val = 0.f;
            #pragma unroll
            for (int k = 0; k < 8; ++k) if (oidx[k] == tid) val = ovals[k];
            srow[tid] = val;
        }
        if (tid < TOPK) out[(size_t)NT * NE + (size_t)tg * TOPK + tid] = (float)oidx[tid];
        __syncthreads();
    }
}

extern "C" void kernel_launch(void* const* d_in, const int* in_sizes, int n_in,
                              void* d_out, int out_size, void* d_ws, size_t ws_size,
                              hipStream_t stream) {
    const float* X = (const float*)d_in[0];
    const float* W = (const float*)d_in[1];
    float* out = (float*)d_out;
    unsigned char* wsb = (unsigned char*)d_ws;
    unsigned short* Wt = (unsigned short*)(wsb + WS_W_OFF);

    hipMemsetAsync(d_ws, 0, 64, stream);
    prep_w_kernel<<<256, 256, 0, stream>>>(W, Wt);
    router_gemm_kernel<<<NT / BTOK, 512, 0, stream>>>(X, Wt, out, (unsigned int*)d_ws);
    finalize_kernel<<<1024, 256, 0, stream>>>(X, W, out, (const unsigned int*)d_ws);
}